// Round 4
// baseline (2440.045 us; speedup 1.0000x reference)
//
#include <hip/hip_runtime.h>
#include <hip/hip_bf16.h>

#define N_NODES 40000
#define INIT_D  100
#define DD      200
#define FF      4
#define EE      800000
#define NRELS   800
#define BB      2048
#define H2D     100
#define FD      800   // F*D

typedef __hip_bfloat16 bf16;
typedef unsigned char u8;

__device__ __forceinline__ float b2f(bf16 v) { return __bfloat162float(v); }

// ---------------- setup: zero counters/cursor/loss ----------------
__global__ __launch_bounds__(256) void zero_kernel(int* count, int* cursor, double* loss) {
    int idx = blockIdx.x * 256 + threadIdx.x;
    if (idx < N_NODES) { count[idx] = 0; cursor[idx] = 0; }
    if (idx == 0) *loss = 0.0;
}

// ---------------- x0 = tanh(init_embed @ pca_w + pca_b) -> f32 out_x ----------------
// grid (13, 2500), block 64. Block: 16 rows x 64 cols.
__global__ __launch_bounds__(64) void pca_kernel(const float* __restrict__ emb,
                                                 const float* __restrict__ pw,
                                                 const float* __restrict__ pb,
                                                 float* __restrict__ x) {
    __shared__ float es[16][INIT_D];
    int r0 = blockIdx.y * 16;
    int c  = blockIdx.x * 64 + threadIdx.x;
    for (int idx = threadIdx.x; idx < 16 * INIT_D; idx += 64) {
        int r = idx / INIT_D, k = idx % INIT_D;
        es[r][k] = emb[(size_t)(r0 + r) * INIT_D + k];
    }
    __syncthreads();
    if (c >= FD) return;
    float acc[16];
#pragma unroll
    for (int r = 0; r < 16; r++) acc[r] = 0.f;
    for (int k = 0; k < INIT_D; k++) {
        float w = pw[k * FD + c];
#pragma unroll
        for (int r = 0; r < 16; r++) acc[r] += es[r][k] * w;
    }
    float bias = pb[c];
#pragma unroll
    for (int r = 0; r < 16; r++)
        x[(size_t)(r0 + r) * FD + c] = tanhf(acc[r] + bias);
}

// ---------------- kw = softmax_F(leaky(x @ cw_w)) -> u8 ----------------
// block 256 = 4 waves, each wave one node. grid 10000.
__global__ __launch_bounds__(256) void kw_kernel(const float* __restrict__ x,
                                                 const float* __restrict__ cw,
                                                 u8* __restrict__ kw) {
    int wave = threadIdx.x >> 6, lane = threadIdx.x & 63;
    int n = blockIdx.x * 4 + wave;
    const float* xp = x + (size_t)n * FD;
    float acc[4][4];
#pragma unroll
    for (int f = 0; f < 4; f++)
#pragma unroll
        for (int i = 0; i < 4; i++) acc[f][i] = 0.f;
    for (int k = 0; k < DD; k++) {
        float xv0 = xp[k], xv1 = xp[DD + k];
        float xv2 = xp[2 * DD + k], xv3 = xp[3 * DD + k];
#pragma unroll
        for (int i = 0; i < 4; i++) {
            int d = i * 64 + lane;
            float w = (d < DD) ? cw[k * DD + d] : 0.f;
            acc[0][i] += xv0 * w; acc[1][i] += xv1 * w;
            acc[2][i] += xv2 * w; acc[3][i] += xv3 * w;
        }
    }
    u8* kwp = kw + (size_t)n * FD;
#pragma unroll
    for (int i = 0; i < 4; i++) {
        int d = i * 64 + lane;
        if (d >= DD) continue;
        float v0 = acc[0][i], v1 = acc[1][i], v2 = acc[2][i], v3 = acc[3][i];
        v0 = v0 > 0.f ? v0 : 0.2f * v0;
        v1 = v1 > 0.f ? v1 : 0.2f * v1;
        v2 = v2 > 0.f ? v2 : 0.2f * v2;
        v3 = v3 > 0.f ? v3 : 0.2f * v3;
        float m = fmaxf(fmaxf(v0, v1), fmaxf(v2, v3));
        float e0 = __expf(v0 - m), e1 = __expf(v1 - m), e2 = __expf(v2 - m), e3 = __expf(v3 - m);
        float inv = 1.f / (e0 + e1 + e2 + e3);
        kwp[d]          = (u8)(e0 * inv * 255.f + 0.5f);
        kwp[DD + d]     = (u8)(e1 * inv * 255.f + 0.5f);
        kwp[2 * DD + d] = (u8)(e2 * inv * 255.f + 0.5f);
        kwp[3 * DD + d] = (u8)(e3 * inv * 255.f + 0.5f);
    }
}

// ---------------- CSR build ----------------
__global__ __launch_bounds__(256) void count_kernel(const int* __restrict__ dst, int* count) {
    int e = blockIdx.x * 256 + threadIdx.x;   // grid exact: 800000
    atomicAdd(&count[dst[e]], 1);
}

__global__ __launch_bounds__(1024) void scan_kernel(const int* __restrict__ count, int* __restrict__ offs) {
    __shared__ int buf[1024];
    __shared__ int carry_s;
    int tid = threadIdx.x;
    if (tid == 0) { carry_s = 0; offs[0] = 0; }
    __syncthreads();
    for (int base = 0; base < 40960; base += 1024) {
        int i = base + tid;
        int v = (i < N_NODES) ? count[i] : 0;
        buf[tid] = v;
        __syncthreads();
        for (int off = 1; off < 1024; off <<= 1) {
            int t = (tid >= off) ? buf[tid - off] : 0;
            __syncthreads();
            buf[tid] += t;
            __syncthreads();
        }
        int incl = buf[tid] + carry_s;
        if (i < N_NODES) offs[i + 1] = incl;
        __syncthreads();
        if (tid == 1023) carry_s = incl;
        __syncthreads();
    }
}

__global__ __launch_bounds__(256) void scatter_kernel(const int* __restrict__ src,
                                                      const int* __restrict__ dst,
                                                      const int* __restrict__ etyp,
                                                      const int* __restrict__ offs,
                                                      int* cursor,
                                                      int* __restrict__ csrc, int* __restrict__ cet) {
    int e = blockIdx.x * 256 + threadIdx.x;   // grid exact
    int d = dst[e];
    int p = offs[d] + atomicAdd(&cursor[d], 1);
    csrc[p] = src[e];
    cet[p]  = etyp[e];
}

// ---------------- sliced graph aggregation (one wave per node, slice f) ----------------
// xall: f32 [N, FD] (the d_out x region). r: f32 [NRELS, DD]. Writes xtmp [N, DD] bf16.
__global__ __launch_bounds__(256) void agg_kernel(const float* __restrict__ xall,
                                                  const u8* __restrict__ kw,
                                                  const float* __restrict__ r,
                                                  const int* __restrict__ offs,
                                                  const int* __restrict__ csrc,
                                                  const int* __restrict__ cet,
                                                  bf16* __restrict__ xtmp,
                                                  int f) {
    int n    = blockIdx.x * 4 + (threadIdx.x >> 6);   // 40000 waves
    int lane = threadIdx.x & 63;
    const float* xdp = xall + (size_t)n * FD + f * DD;
    float xd[4];
#pragma unroll
    for (int i = 0; i < 4; i++) {
        int d = i * 64 + lane;
        xd[i] = (d < DD) ? xdp[d] : 0.f;
    }
    float M = -INFINITY, S = 0.f;
    float A0 = 0.f, A1 = 0.f, A2 = 0.f, A3 = 0.f;
    int e0 = offs[n], e1 = offs[n + 1];
    for (int e = e0; e < e1; ++e) {
        int s = csrc[e], t = cet[e];
        const float* xsp = xall + (size_t)s * FD + f * DD;
        const float* rp = r + t * DD;
        float mm[4];
        float p = 0.f;
#pragma unroll
        for (int i = 0; i < 4; i++) {
            int d = i * 64 + lane;
            float xs = (d < DD) ? xsp[d] : 0.f;
            float rr = (d < DD) ? rp[d] : 0.f;
            mm[i] = xs * rr;
            p += mm[i] * xd[i];
        }
#pragma unroll
        for (int o = 32; o > 0; o >>= 1) p += __shfl_xor(p, o, 64);
        float logit = p > 0.f ? p : 0.2f * p;
        float nm = fmaxf(M, logit);
        float sc = __expf(M - nm);       // first iter: exp(-inf)=0
        float w  = __expf(logit - nm);
        S  = S * sc + w;
        A0 = A0 * sc + w * mm[0];
        A1 = A1 * sc + w * mm[1];
        A2 = A2 * sc + w * mm[2];
        A3 = A3 * sc + w * mm[3];
        M = nm;
    }
    float inv = 1.f / (S + 1e-16f);
    const u8* kwp = kw + (size_t)n * FD + f * DD;
    bf16* xo = xtmp + (size_t)n * DD;
    float A[4] = {A0, A1, A2, A3};
#pragma unroll
    for (int i = 0; i < 4; i++) {
        int d = i * 64 + lane;
        if (d < DD) {
            float kv = (float)kwp[d] * (1.f / 255.f);
            xo[d] = __float2bfloat16(tanhf(A[i] * inv) * kv);
        }
    }
}

// copy xtmp slice back into xall slice f (bf16 -> f32)
__global__ __launch_bounds__(256) void copyback_kernel(const bf16* __restrict__ xtmp,
                                                       float* __restrict__ xall, int f) {
    int idx = blockIdx.x * 256 + threadIdx.x;   // grid exact: 8,000,000
    int n = idx / DD, d = idx % DD;
    xall[(size_t)n * FD + f * DD + d] = b2f(xtmp[idx]);
}

// ---------------- r1 = init_rel @ w_rel[0]  (all f32) ----------------
__global__ __launch_bounds__(256) void rmul_kernel(const float* __restrict__ r0,
                                                   const float* __restrict__ w,
                                                   float* __restrict__ r1) {
    __shared__ float row[DD];
    int n = blockIdx.x;
    if (threadIdx.x < DD) row[threadIdx.x] = r0[n * DD + threadIdx.x];
    __syncthreads();
    int d = threadIdx.x;
    if (d >= DD) return;
    float acc = 0.f;
    for (int k = 0; k < DD; k++) acc += row[k] * w[k * DD + d];
    r1[n * DD + d] = acc;
}

// ---------------- outputs (all f32) ----------------
__global__ __launch_bounds__(256) void subemb_kernel(const float* __restrict__ x,
                                                     const int* __restrict__ sub,
                                                     float* __restrict__ out) {
    int idx = blockIdx.x * 256 + threadIdx.x;   // grid exact: 1638400
    int b = idx / FD, c = idx % FD;
    out[idx] = x[(size_t)sub[b] * FD + c];
}

__global__ __launch_bounds__(256) void relemb_kernel(const float* __restrict__ ir,
                                                     const int* __restrict__ rel,
                                                     float* __restrict__ out) {
    int idx = blockIdx.x * 256 + threadIdx.x;   // grid exact: 1638400
    int b = idx / FD, d = idx % DD;
    out[idx] = ir[(size_t)rel[b] * DD + d];
}

// ---------------- CLUB loss (reads f32 sub_emb from d_out) ----------------
// grid (256, 6), block 256. Each block: one pair, 8 batch rows.
__global__ __launch_bounds__(256) void club_kernel(const float* __restrict__ se,
                                                   const int* __restrict__ perm,
                                                   const float* __restrict__ mu_w1, const float* __restrict__ mu_b1,
                                                   const float* __restrict__ mu_w2, const float* __restrict__ mu_b2,
                                                   const float* __restrict__ lv_w1, const float* __restrict__ lv_b1,
                                                   const float* __restrict__ lv_w2, const float* __restrict__ lv_b2,
                                                   double* loss) {
    const int PI[6] = {0, 0, 0, 1, 1, 2};
    const int PJ[6] = {1, 2, 3, 2, 3, 3};
    int p = blockIdx.y;
    int i = PI[p], j = PJ[p];
    __shared__ float xi[DD], yj[DD], yjp[DD], h1m[H2D], h1v[H2D];
    __shared__ float wsum[4];
    float psum = 0.f;
    for (int rr = 0; rr < 8; ++rr) {
        int b = blockIdx.x * 8 + rr;
        int bp = perm[b];
        if (threadIdx.x < DD) {
            int t = threadIdx.x;
            xi[t]  = se[(size_t)b * FD + i * DD + t];
            yj[t]  = se[(size_t)b * FD + j * DD + t];
            yjp[t] = se[(size_t)bp * FD + j * DD + t];
        }
        __syncthreads();
        if (threadIdx.x < H2D) {
            int c = threadIdx.x;
            float a1 = mu_b1[p * H2D + c];
            float a2 = lv_b1[p * H2D + c];
            for (int d = 0; d < DD; d++) {
                float xv = xi[d];
                a1 += xv * mu_w1[(size_t)p * DD * H2D + d * H2D + c];
                a2 += xv * lv_w1[(size_t)p * DD * H2D + d * H2D + c];
            }
            h1m[c] = fmaxf(a1, 0.f);
            h1v[c] = fmaxf(a2, 0.f);
        }
        __syncthreads();
        if (threadIdx.x < DD) {
            int d = threadIdx.x;
            float m = mu_b2[p * DD + d];
            float v = lv_b2[p * DD + d];
            for (int c = 0; c < H2D; c++) {
                m += h1m[c] * mu_w2[(size_t)p * H2D * DD + c * DD + d];
                v += h1v[c] * lv_w2[(size_t)p * H2D * DD + c * DD + d];
            }
            float lv = tanhf(v);
            float ivr = __expf(-lv);
            float d1 = m - yj[d], d2 = m - yjp[d];
            psum += (d2 * d2 - d1 * d1) * ivr;
        }
        __syncthreads();
    }
    float v = psum;
#pragma unroll
    for (int o = 32; o > 0; o >>= 1) v += __shfl_xor(v, o, 64);
    if ((threadIdx.x & 63) == 0) wsum[threadIdx.x >> 6] = v;
    __syncthreads();
    if (threadIdx.x == 0) {
        double t = (double)wsum[0] + (double)wsum[1] + (double)wsum[2] + (double)wsum[3];
        atomicAdd(loss, t / (2.0 * (double)BB));
    }
}

__global__ void loss_out_kernel(const double* loss, float* out) {
    if (threadIdx.x == 0 && blockIdx.x == 0)
        out[0] = (float)(*loss);
}

// ---------------- launch ----------------
extern "C" void kernel_launch(void* const* d_in, const int* in_sizes, int n_in,
                              void* d_out, int out_size, void* d_ws, size_t ws_size,
                              hipStream_t stream) {
    const int* sub  = (const int*)d_in[0];
    const int* rel  = (const int*)d_in[1];
    const int* eidx = (const int*)d_in[2];   // [0..E) src, [E..2E) dst
    const int* etyp = (const int*)d_in[3];
    const int* perm = (const int*)d_in[4];
    const float* init_embed = (const float*)d_in[5];
    const float* init_rel   = (const float*)d_in[6];
    const float* pca_w = (const float*)d_in[7];
    const float* pca_b = (const float*)d_in[8];
    const float* cw_w  = (const float*)d_in[9];
    const float* w_rel = (const float*)d_in[10];
    const float* mu_w1 = (const float*)d_in[11];
    const float* mu_b1 = (const float*)d_in[12];
    const float* mu_w2 = (const float*)d_in[13];
    const float* mu_b2 = (const float*)d_in[14];
    const float* lv_w1 = (const float*)d_in[15];
    const float* lv_b1 = (const float*)d_in[16];
    const float* lv_w2 = (const float*)d_in[17];
    const float* lv_b2 = (const float*)d_in[18];

    float* out = (float*)d_out;
    const size_t OFF_SUB = 0;
    const size_t OFF_REL = 1638400;
    const size_t OFF_X   = 3276800;
    const size_t OFF_MI  = 35276800;
    float* xall = out + OFF_X;    // x lives in the output region (f32)

    // workspace layout (~55.4 MB total)
    char* w = (char*)d_ws;
    bf16* xtmp = (bf16*)w;  w += (size_t)N_NODES * DD * 2;   // 16 MB
    u8*   kw   = (u8*)w;    w += (size_t)N_NODES * FD;       // 32 MB
    float* r1  = (float*)w; w += NRELS * DD * 4;             // 0.64 MB
    int* csrc  = (int*)w;   w += EE * 4;                     // 3.2 MB
    int* cet   = (int*)w;   w += EE * 4;                     // 3.2 MB
    int* count = (int*)w;   w += N_NODES * 4;                // 0.16 MB
    int* offs  = (int*)w;   w += (N_NODES + 16) * 4;         // 0.16 MB
    int* cursor= (int*)w;   w += N_NODES * 4;                // 0.16 MB
    double* loss = (double*)w; w += 256;

    const int* src = eidx;
    const int* dst = eidx + EE;

    hipLaunchKernelGGL(zero_kernel, dim3(157), dim3(256), 0, stream, count, cursor, loss);
    hipLaunchKernelGGL(pca_kernel, dim3(13, 2500), dim3(64), 0, stream, init_embed, pca_w, pca_b, xall);
    hipLaunchKernelGGL(kw_kernel, dim3(10000), dim3(256), 0, stream, xall, cw_w, kw);
    hipLaunchKernelGGL(count_kernel, dim3(3125), dim3(256), 0, stream, dst, count);
    hipLaunchKernelGGL(scan_kernel, dim3(1), dim3(1024), 0, stream, count, offs);
    hipLaunchKernelGGL(scatter_kernel, dim3(3125), dim3(256), 0, stream, src, dst, etyp, offs, cursor, csrc, cet);

    // r1 = init_rel @ w_rel[0]
    hipLaunchKernelGGL(rmul_kernel, dim3(800), dim3(256), 0, stream, init_rel, w_rel, r1);

    // layer 0 (uses init_rel), sliced by f, ping through xtmp
    for (int f = 0; f < FF; f++) {
        hipLaunchKernelGGL(agg_kernel, dim3(10000), dim3(256), 0, stream,
                           xall, kw, init_rel, offs, csrc, cet, xtmp, f);
        hipLaunchKernelGGL(copyback_kernel, dim3(31250), dim3(256), 0, stream, xtmp, xall, f);
    }
    // layer 1 (uses r1)
    for (int f = 0; f < FF; f++) {
        hipLaunchKernelGGL(agg_kernel, dim3(10000), dim3(256), 0, stream,
                           xall, kw, r1, offs, csrc, cet, xtmp, f);
        hipLaunchKernelGGL(copyback_kernel, dim3(31250), dim3(256), 0, stream, xtmp, xall, f);
    }

    hipLaunchKernelGGL(subemb_kernel, dim3(6400), dim3(256), 0, stream, xall, sub, out + OFF_SUB);
    hipLaunchKernelGGL(relemb_kernel, dim3(6400), dim3(256), 0, stream, init_rel, rel, out + OFF_REL);
    hipLaunchKernelGGL(club_kernel, dim3(256, 6), dim3(256), 0, stream, out + OFF_SUB, perm,
                       mu_w1, mu_b1, mu_w2, mu_b2, lv_w1, lv_b1, lv_w2, lv_b2, loss);
    hipLaunchKernelGGL(loss_out_kernel, dim3(1), dim3(64), 0, stream, loss, out + OFF_MI);
}

// Round 5
// 1850.524 us; speedup vs baseline: 1.3186x; 1.3186x over previous
//
#include <hip/hip_runtime.h>
#include <hip/hip_bf16.h>

#define N_NODES 40000
#define INIT_D  100
#define DD      200
#define FF      4
#define EE      800000
#define NRELS   800
#define BB      2048
#define H2D     100
#define FD      800   // F*D

typedef __hip_bfloat16 bf16;
typedef unsigned char u8;
typedef unsigned int u32;

__device__ __forceinline__ float b2f(bf16 v) { return __bfloat162float(v); }

// ---------------- setup: zero counters/cursor/loss ----------------
__global__ __launch_bounds__(256) void zero_kernel(int* count, int* cursor, double* loss) {
    int idx = blockIdx.x * 256 + threadIdx.x;
    if (idx < N_NODES) { count[idx] = 0; cursor[idx] = 0; }
    if (idx == 0) *loss = 0.0;
}

// ---------------- x0 = tanh(init_embed @ pca_w + pca_b) ----------------
// grid (13, 2500), block 64. mode 0: write bf16 xb; mode 1: write f32 xf.
__global__ __launch_bounds__(64) void pca_kernel(const float* __restrict__ emb,
                                                 const float* __restrict__ pw,
                                                 const float* __restrict__ pb,
                                                 bf16* __restrict__ xb,
                                                 float* __restrict__ xf,
                                                 int mode) {
    __shared__ float es[16][INIT_D];
    int r0 = blockIdx.y * 16;
    int c  = blockIdx.x * 64 + threadIdx.x;
    for (int idx = threadIdx.x; idx < 16 * INIT_D; idx += 64) {
        int r = idx / INIT_D, k = idx % INIT_D;
        es[r][k] = emb[(size_t)(r0 + r) * INIT_D + k];
    }
    __syncthreads();
    if (c >= FD) return;
    float acc[16];
#pragma unroll
    for (int r = 0; r < 16; r++) acc[r] = 0.f;
    for (int k = 0; k < INIT_D; k++) {
        float w = pw[k * FD + c];
#pragma unroll
        for (int r = 0; r < 16; r++) acc[r] += es[r][k] * w;
    }
    float bias = pb[c];
#pragma unroll
    for (int r = 0; r < 16; r++) {
        float v = tanhf(acc[r] + bias);
        if (mode == 0) xb[(size_t)(r0 + r) * FD + c] = __float2bfloat16(v);
        else           xf[(size_t)(r0 + r) * FD + c] = v;
    }
}

// ---------------- kw fast: blocked GEMM, wave = 16 rows (4 nodes) x 200 cols ----------
// xr viewed as [160000, 200] bf16 (row = n*4+f). grid 2500, block 256 (4 waves).
__global__ __launch_bounds__(256) void kw_fast(const bf16* __restrict__ xr,
                                               const float* __restrict__ cw,
                                               u8* __restrict__ kwout) {
    __shared__ float as[4][16][52];
    int wv = threadIdx.x >> 6, lane = threadIdx.x & 63;
    int g = blockIdx.x * 4 + wv;     // node-group (4 nodes), 0..9999
    size_t rowbase = (size_t)g * 16;
    float acc[16][4];
#pragma unroll
    for (int r = 0; r < 16; r++)
#pragma unroll
        for (int i = 0; i < 4; i++) acc[r][i] = 0.f;
    int cc[4], cl[4];
#pragma unroll
    for (int i = 0; i < 4; i++) { cc[i] = i * 64 + lane; cl[i] = cc[i] < DD ? cc[i] : DD - 1; }
    for (int kc = 0; kc < 4; kc++) {
        for (int idx = lane; idx < 800; idx += 64) {
            int rr = idx / 50, kk = idx - rr * 50;
            as[wv][rr][kk] = b2f(xr[(rowbase + rr) * DD + kc * 50 + kk]);
        }
        __syncthreads();
        for (int kk = 0; kk < 50; kk++) {
            int k = kc * 50 + kk;
            float w0 = cw[k * DD + cl[0]];
            float w1 = cw[k * DD + cl[1]];
            float w2 = cw[k * DD + cl[2]];
            float w3 = cw[k * DD + cl[3]];
#pragma unroll
            for (int r = 0; r < 16; r++) {
                float a = as[wv][r][kk];
                acc[r][0] += a * w0; acc[r][1] += a * w1;
                acc[r][2] += a * w2; acc[r][3] += a * w3;
            }
        }
        __syncthreads();
    }
#pragma unroll
    for (int j = 0; j < 4; j++) {
        int n = g * 4 + j;
#pragma unroll
        for (int i = 0; i < 4; i++) {
            if (cc[i] >= DD) continue;
            float v0 = acc[j * 4 + 0][i], v1 = acc[j * 4 + 1][i];
            float v2 = acc[j * 4 + 2][i], v3 = acc[j * 4 + 3][i];
            v0 = v0 > 0.f ? v0 : 0.2f * v0;
            v1 = v1 > 0.f ? v1 : 0.2f * v1;
            v2 = v2 > 0.f ? v2 : 0.2f * v2;
            v3 = v3 > 0.f ? v3 : 0.2f * v3;
            float m = fmaxf(fmaxf(v0, v1), fmaxf(v2, v3));
            float e0 = __expf(v0 - m), e1 = __expf(v1 - m);
            float e2 = __expf(v2 - m), e3 = __expf(v3 - m);
            float inv = 1.f / (e0 + e1 + e2 + e3);
            size_t base = (size_t)n * FD + cc[i];
            kwout[base]          = (u8)(e0 * inv * 255.f + 0.5f);
            kwout[base + DD]     = (u8)(e1 * inv * 255.f + 0.5f);
            kwout[base + 2 * DD] = (u8)(e2 * inv * 255.f + 0.5f);
            kwout[base + 3 * DD] = (u8)(e3 * inv * 255.f + 0.5f);
        }
    }
}

// ---------------- kw fallback: wave-per-node, f32 x ----------------
__global__ __launch_bounds__(256) void kw_old(const float* __restrict__ x,
                                              const float* __restrict__ cw,
                                              u8* __restrict__ kw) {
    int wave = threadIdx.x >> 6, lane = threadIdx.x & 63;
    int n = blockIdx.x * 4 + wave;
    const float* xp = x + (size_t)n * FD;
    float acc[4][4];
#pragma unroll
    for (int f = 0; f < 4; f++)
#pragma unroll
        for (int i = 0; i < 4; i++) acc[f][i] = 0.f;
    for (int k = 0; k < DD; k++) {
        float xv0 = xp[k], xv1 = xp[DD + k];
        float xv2 = xp[2 * DD + k], xv3 = xp[3 * DD + k];
#pragma unroll
        for (int i = 0; i < 4; i++) {
            int d = i * 64 + lane;
            float w = (d < DD) ? cw[k * DD + d] : 0.f;
            acc[0][i] += xv0 * w; acc[1][i] += xv1 * w;
            acc[2][i] += xv2 * w; acc[3][i] += xv3 * w;
        }
    }
    u8* kwp = kw + (size_t)n * FD;
#pragma unroll
    for (int i = 0; i < 4; i++) {
        int d = i * 64 + lane;
        if (d >= DD) continue;
        float v0 = acc[0][i], v1 = acc[1][i], v2 = acc[2][i], v3 = acc[3][i];
        v0 = v0 > 0.f ? v0 : 0.2f * v0;
        v1 = v1 > 0.f ? v1 : 0.2f * v1;
        v2 = v2 > 0.f ? v2 : 0.2f * v2;
        v3 = v3 > 0.f ? v3 : 0.2f * v3;
        float m = fmaxf(fmaxf(v0, v1), fmaxf(v2, v3));
        float e0 = __expf(v0 - m), e1 = __expf(v1 - m), e2 = __expf(v2 - m), e3 = __expf(v3 - m);
        float inv = 1.f / (e0 + e1 + e2 + e3);
        kwp[d]          = (u8)(e0 * inv * 255.f + 0.5f);
        kwp[DD + d]     = (u8)(e1 * inv * 255.f + 0.5f);
        kwp[2 * DD + d] = (u8)(e2 * inv * 255.f + 0.5f);
        kwp[3 * DD + d] = (u8)(e3 * inv * 255.f + 0.5f);
    }
}

// ---------------- CSR build (packed: etype<<16 | src) ----------------
__global__ __launch_bounds__(256) void count_kernel(const int* __restrict__ dst, int* count) {
    int e = blockIdx.x * 256 + threadIdx.x;
    atomicAdd(&count[dst[e]], 1);
}

__global__ __launch_bounds__(1024) void scan_kernel(const int* __restrict__ count, int* __restrict__ offs) {
    __shared__ int buf[1024];
    __shared__ int carry_s;
    int tid = threadIdx.x;
    if (tid == 0) { carry_s = 0; offs[0] = 0; }
    __syncthreads();
    for (int base = 0; base < 40960; base += 1024) {
        int i = base + tid;
        int v = (i < N_NODES) ? count[i] : 0;
        buf[tid] = v;
        __syncthreads();
        for (int off = 1; off < 1024; off <<= 1) {
            int t = (tid >= off) ? buf[tid - off] : 0;
            __syncthreads();
            buf[tid] += t;
            __syncthreads();
        }
        int incl = buf[tid] + carry_s;
        if (i < N_NODES) offs[i + 1] = incl;
        __syncthreads();
        if (tid == 1023) carry_s = incl;
        __syncthreads();
    }
}

__global__ __launch_bounds__(256) void scatter_kernel(const int* __restrict__ src,
                                                      const int* __restrict__ dst,
                                                      const int* __restrict__ etyp,
                                                      const int* __restrict__ offs,
                                                      int* cursor,
                                                      u32* __restrict__ ep) {
    int e = blockIdx.x * 256 + threadIdx.x;
    int d = dst[e];
    int p = offs[d] + atomicAdd(&cursor[d], 1);
    ep[p] = ((u32)etyp[e] << 16) | (u32)src[e];
}

// ---------------- fast agg: wave per node, all 4 f, bf16 in/out ----------------
__global__ __launch_bounds__(256) void agg_fast(const bf16* __restrict__ xin,
                                                const u8* __restrict__ kwv,
                                                const float* __restrict__ r,
                                                const int* __restrict__ offs,
                                                const u32* __restrict__ ep,
                                                bf16* __restrict__ xout) {
    int n    = blockIdx.x * 4 + (threadIdx.x >> 6);   // 40000 waves
    int lane = threadIdx.x & 63;
    float xd[4][4], A[4][4], S[4], M[4];
#pragma unroll
    for (int f = 0; f < 4; f++) {
        S[f] = 0.f; M[f] = -INFINITY;
#pragma unroll
        for (int i = 0; i < 4; i++) {
            int d = i * 64 + lane;
            xd[f][i] = (d < DD) ? b2f(xin[(size_t)n * FD + f * DD + d]) : 0.f;
            A[f][i] = 0.f;
        }
    }
    int e0 = offs[n], e1 = offs[n + 1];
    for (int e = e0; e < e1; ++e) {
        u32 wrd = ep[e];
        int s = wrd & 0xFFFF, t = wrd >> 16;
        const bf16* xsp = xin + (size_t)s * FD;
        const float* rp = r + t * DD;
        float rr[4];
#pragma unroll
        for (int i = 0; i < 4; i++) {
            int d = i * 64 + lane;
            rr[i] = (d < DD) ? rp[d] : 0.f;
        }
        float mm[4][4];
        float p0 = 0.f, p1 = 0.f, p2 = 0.f, p3 = 0.f;
#pragma unroll
        for (int i = 0; i < 4; i++) {
            int d = i * 64 + lane;
            float x0 = (d < DD) ? b2f(xsp[0 * DD + d]) : 0.f;
            float x1 = (d < DD) ? b2f(xsp[1 * DD + d]) : 0.f;
            float x2 = (d < DD) ? b2f(xsp[2 * DD + d]) : 0.f;
            float x3 = (d < DD) ? b2f(xsp[3 * DD + d]) : 0.f;
            mm[0][i] = x0 * rr[i]; p0 += mm[0][i] * xd[0][i];
            mm[1][i] = x1 * rr[i]; p1 += mm[1][i] * xd[1][i];
            mm[2][i] = x2 * rr[i]; p2 += mm[2][i] * xd[2][i];
            mm[3][i] = x3 * rr[i]; p3 += mm[3][i] * xd[3][i];
        }
#pragma unroll
        for (int o = 32; o > 0; o >>= 1) {
            p0 += __shfl_xor(p0, o, 64);
            p1 += __shfl_xor(p1, o, 64);
            p2 += __shfl_xor(p2, o, 64);
            p3 += __shfl_xor(p3, o, 64);
        }
        float pv[4] = {p0, p1, p2, p3};
#pragma unroll
        for (int f = 0; f < 4; f++) {
            float lg = pv[f] > 0.f ? pv[f] : 0.2f * pv[f];
            float nm = fmaxf(M[f], lg);
            float sc = __expf(M[f] - nm);
            float w  = __expf(lg - nm);
            S[f] = S[f] * sc + w;
#pragma unroll
            for (int i = 0; i < 4; i++) A[f][i] = A[f][i] * sc + w * mm[f][i];
            M[f] = nm;
        }
    }
#pragma unroll
    for (int f = 0; f < 4; f++) {
        float inv = 1.f / (S[f] + 1e-16f);
#pragma unroll
        for (int i = 0; i < 4; i++) {
            int d = i * 64 + lane;
            if (d < DD) {
                size_t o = (size_t)n * FD + f * DD + d;
                float kv = (float)kwv[o] * (1.f / 255.f);
                xout[o] = __float2bfloat16(tanhf(A[f][i] * inv) * kv);
            }
        }
    }
}

// ---------------- fallback sliced agg (f32 x in out region, bf16 xtmp) ----------------
__global__ __launch_bounds__(256) void agg_sliced(const float* __restrict__ xall,
                                                  const u8* __restrict__ kw,
                                                  const float* __restrict__ r,
                                                  const int* __restrict__ offs,
                                                  const u32* __restrict__ ep,
                                                  bf16* __restrict__ xtmp,
                                                  int f) {
    int n    = blockIdx.x * 4 + (threadIdx.x >> 6);
    int lane = threadIdx.x & 63;
    const float* xdp = xall + (size_t)n * FD + f * DD;
    float xd[4];
#pragma unroll
    for (int i = 0; i < 4; i++) {
        int d = i * 64 + lane;
        xd[i] = (d < DD) ? xdp[d] : 0.f;
    }
    float M = -INFINITY, S = 0.f;
    float A0 = 0.f, A1 = 0.f, A2 = 0.f, A3 = 0.f;
    int e0 = offs[n], e1 = offs[n + 1];
    for (int e = e0; e < e1; ++e) {
        u32 wrd = ep[e];
        int s = wrd & 0xFFFF, t = wrd >> 16;
        const float* xsp = xall + (size_t)s * FD + f * DD;
        const float* rp = r + t * DD;
        float mm[4];
        float p = 0.f;
#pragma unroll
        for (int i = 0; i < 4; i++) {
            int d = i * 64 + lane;
            float xs = (d < DD) ? xsp[d] : 0.f;
            float rrv = (d < DD) ? rp[d] : 0.f;
            mm[i] = xs * rrv;
            p += mm[i] * xd[i];
        }
#pragma unroll
        for (int o = 32; o > 0; o >>= 1) p += __shfl_xor(p, o, 64);
        float logit = p > 0.f ? p : 0.2f * p;
        float nm = fmaxf(M, logit);
        float sc = __expf(M - nm);
        float w  = __expf(logit - nm);
        S  = S * sc + w;
        A0 = A0 * sc + w * mm[0];
        A1 = A1 * sc + w * mm[1];
        A2 = A2 * sc + w * mm[2];
        A3 = A3 * sc + w * mm[3];
        M = nm;
    }
    float inv = 1.f / (S + 1e-16f);
    const u8* kwp = kw + (size_t)n * FD + f * DD;
    bf16* xo = xtmp + (size_t)n * DD;
    float A[4] = {A0, A1, A2, A3};
#pragma unroll
    for (int i = 0; i < 4; i++) {
        int d = i * 64 + lane;
        if (d < DD) {
            float kv = (float)kwp[d] * (1.f / 255.f);
            xo[d] = __float2bfloat16(tanhf(A[i] * inv) * kv);
        }
    }
}

__global__ __launch_bounds__(256) void copyback_kernel(const bf16* __restrict__ xtmp,
                                                       float* __restrict__ xall, int f) {
    int idx = blockIdx.x * 256 + threadIdx.x;   // 8,000,000
    int n = idx / DD, d = idx % DD;
    xall[(size_t)n * FD + f * DD + d] = b2f(xtmp[idx]);
}

// ---------------- cvt bf16 -> f32 (fast path final x) ----------------
__global__ __launch_bounds__(256) void cvt_kernel(const bf16* __restrict__ src, float* __restrict__ dst) {
    size_t idx = (size_t)blockIdx.x * 256 + threadIdx.x;   // 32,000,000
    dst[idx] = b2f(src[idx]);
}

// ---------------- r1 = init_rel @ w_rel[0] ----------------
__global__ __launch_bounds__(256) void rmul_kernel(const float* __restrict__ r0,
                                                   const float* __restrict__ w,
                                                   float* __restrict__ r1) {
    __shared__ float row[DD];
    int n = blockIdx.x;
    if (threadIdx.x < DD) row[threadIdx.x] = r0[n * DD + threadIdx.x];
    __syncthreads();
    int d = threadIdx.x;
    if (d >= DD) return;
    float acc = 0.f;
    for (int k = 0; k < DD; k++) acc += row[k] * w[k * DD + d];
    r1[n * DD + d] = acc;
}

// ---------------- outputs (f32) ----------------
__global__ __launch_bounds__(256) void subemb_kernel(const float* __restrict__ x,
                                                     const int* __restrict__ sub,
                                                     float* __restrict__ out) {
    int idx = blockIdx.x * 256 + threadIdx.x;   // 1,638,400
    int b = idx / FD, c = idx % FD;
    out[idx] = x[(size_t)sub[b] * FD + c];
}

__global__ __launch_bounds__(256) void relemb_kernel(const float* __restrict__ ir,
                                                     const int* __restrict__ rel,
                                                     float* __restrict__ out) {
    int idx = blockIdx.x * 256 + threadIdx.x;   // 1,638,400
    int b = idx / FD, d = idx % DD;
    out[idx] = ir[(size_t)rel[b] * DD + d];
}

// ---------------- CLUB loss ----------------
__global__ __launch_bounds__(256) void club_kernel(const float* __restrict__ se,
                                                   const int* __restrict__ perm,
                                                   const float* __restrict__ mu_w1, const float* __restrict__ mu_b1,
                                                   const float* __restrict__ mu_w2, const float* __restrict__ mu_b2,
                                                   const float* __restrict__ lv_w1, const float* __restrict__ lv_b1,
                                                   const float* __restrict__ lv_w2, const float* __restrict__ lv_b2,
                                                   double* loss) {
    const int PI[6] = {0, 0, 0, 1, 1, 2};
    const int PJ[6] = {1, 2, 3, 2, 3, 3};
    int p = blockIdx.y;
    int i = PI[p], j = PJ[p];
    __shared__ float xi[DD], yj[DD], yjp[DD], h1m[H2D], h1v[H2D];
    __shared__ float wsum[4];
    float psum = 0.f;
    for (int rr = 0; rr < 8; ++rr) {
        int b = blockIdx.x * 8 + rr;
        int bp = perm[b];
        if (threadIdx.x < DD) {
            int t = threadIdx.x;
            xi[t]  = se[(size_t)b * FD + i * DD + t];
            yj[t]  = se[(size_t)b * FD + j * DD + t];
            yjp[t] = se[(size_t)bp * FD + j * DD + t];
        }
        __syncthreads();
        if (threadIdx.x < H2D) {
            int c = threadIdx.x;
            float a1 = mu_b1[p * H2D + c];
            float a2 = lv_b1[p * H2D + c];
            for (int d = 0; d < DD; d++) {
                float xv = xi[d];
                a1 += xv * mu_w1[(size_t)p * DD * H2D + d * H2D + c];
                a2 += xv * lv_w1[(size_t)p * DD * H2D + d * H2D + c];
            }
            h1m[c] = fmaxf(a1, 0.f);
            h1v[c] = fmaxf(a2, 0.f);
        }
        __syncthreads();
        if (threadIdx.x < DD) {
            int d = threadIdx.x;
            float m = mu_b2[p * DD + d];
            float v = lv_b2[p * DD + d];
            for (int c = 0; c < H2D; c++) {
                m += h1m[c] * mu_w2[(size_t)p * H2D * DD + c * DD + d];
                v += h1v[c] * lv_w2[(size_t)p * H2D * DD + c * DD + d];
            }
            float lv = tanhf(v);
            float ivr = __expf(-lv);
            float d1 = m - yj[d], d2 = m - yjp[d];
            psum += (d2 * d2 - d1 * d1) * ivr;
        }
        __syncthreads();
    }
    float v = psum;
#pragma unroll
    for (int o = 32; o > 0; o >>= 1) v += __shfl_xor(v, o, 64);
    if ((threadIdx.x & 63) == 0) wsum[threadIdx.x >> 6] = v;
    __syncthreads();
    if (threadIdx.x == 0) {
        double t = (double)wsum[0] + (double)wsum[1] + (double)wsum[2] + (double)wsum[3];
        atomicAdd(loss, t / (2.0 * (double)BB));
    }
}

__global__ void loss_out_kernel(const double* loss, float* out) {
    if (threadIdx.x == 0 && blockIdx.x == 0)
        out[0] = (float)(*loss);
}

// ---------------- launch ----------------
extern "C" void kernel_launch(void* const* d_in, const int* in_sizes, int n_in,
                              void* d_out, int out_size, void* d_ws, size_t ws_size,
                              hipStream_t stream) {
    const int* sub  = (const int*)d_in[0];
    const int* rel  = (const int*)d_in[1];
    const int* eidx = (const int*)d_in[2];
    const int* etyp = (const int*)d_in[3];
    const int* perm = (const int*)d_in[4];
    const float* init_embed = (const float*)d_in[5];
    const float* init_rel   = (const float*)d_in[6];
    const float* pca_w = (const float*)d_in[7];
    const float* pca_b = (const float*)d_in[8];
    const float* cw_w  = (const float*)d_in[9];
    const float* w_rel = (const float*)d_in[10];
    const float* mu_w1 = (const float*)d_in[11];
    const float* mu_b1 = (const float*)d_in[12];
    const float* mu_w2 = (const float*)d_in[13];
    const float* mu_b2 = (const float*)d_in[14];
    const float* lv_w1 = (const float*)d_in[15];
    const float* lv_b1 = (const float*)d_in[16];
    const float* lv_w2 = (const float*)d_in[17];
    const float* lv_b2 = (const float*)d_in[18];

    float* out = (float*)d_out;
    const size_t OFF_SUB = 0;
    const size_t OFF_REL = 1638400;
    const size_t OFF_X   = 3276800;
    const size_t OFF_MI  = 35276800;
    float* xall = out + OFF_X;

    const int* src = eidx;
    const int* dst = eidx + EE;

    bool fast = (ws_size >= (size_t)101 * 1000 * 1000);

    char* w = (char*)d_ws;
    bf16* xbf = nullptr;
    bf16* xtmp = nullptr;
    if (fast) { xbf  = (bf16*)w; w += (size_t)N_NODES * FD * 2; }   // 64 MB
    else      { xtmp = (bf16*)w; w += (size_t)N_NODES * DD * 2; }   // 16 MB
    u8*   kwb  = (u8*)w;    w += (size_t)N_NODES * FD;              // 32 MB
    float* r1  = (float*)w; w += NRELS * DD * 4;
    u32* ep    = (u32*)w;   w += EE * 4;
    int* count = (int*)w;   w += N_NODES * 4;
    int* offs  = (int*)w;   w += (N_NODES + 16) * 4;
    int* cursor= (int*)w;   w += N_NODES * 4;
    double* loss = (double*)w; w += 256;

    hipLaunchKernelGGL(zero_kernel, dim3(157), dim3(256), 0, stream, count, cursor, loss);
    hipLaunchKernelGGL(pca_kernel, dim3(13, 2500), dim3(64), 0, stream,
                       init_embed, pca_w, pca_b, xbf, xall, fast ? 0 : 1);
    if (fast) hipLaunchKernelGGL(kw_fast, dim3(2500), dim3(256), 0, stream, xbf, cw_w, kwb);
    else      hipLaunchKernelGGL(kw_old, dim3(10000), dim3(256), 0, stream, xall, cw_w, kwb);
    hipLaunchKernelGGL(count_kernel, dim3(3125), dim3(256), 0, stream, dst, count);
    hipLaunchKernelGGL(scan_kernel, dim3(1), dim3(1024), 0, stream, count, offs);
    hipLaunchKernelGGL(scatter_kernel, dim3(3125), dim3(256), 0, stream, src, dst, etyp, offs, cursor, ep);
    hipLaunchKernelGGL(rmul_kernel, dim3(800), dim3(256), 0, stream, init_rel, w_rel, r1);

    if (fast) {
        bf16* xh = (bf16*)xall;   // out-region x area reused as bf16 ping buffer
        hipLaunchKernelGGL(agg_fast, dim3(10000), dim3(256), 0, stream,
                           xbf, kwb, init_rel, offs, ep, xh);
        hipLaunchKernelGGL(agg_fast, dim3(10000), dim3(256), 0, stream,
                           xh, kwb, r1, offs, ep, xbf);
        hipLaunchKernelGGL(cvt_kernel, dim3(125000), dim3(256), 0, stream, xbf, xall);
    } else {
        for (int f = 0; f < FF; f++) {
            hipLaunchKernelGGL(agg_sliced, dim3(10000), dim3(256), 0, stream,
                               xall, kwb, init_rel, offs, ep, xtmp, f);
            hipLaunchKernelGGL(copyback_kernel, dim3(31250), dim3(256), 0, stream, xtmp, xall, f);
        }
        for (int f = 0; f < FF; f++) {
            hipLaunchKernelGGL(agg_sliced, dim3(10000), dim3(256), 0, stream,
                               xall, kwb, r1, offs, ep, xtmp, f);
            hipLaunchKernelGGL(copyback_kernel, dim3(31250), dim3(256), 0, stream, xtmp, xall, f);
        }
    }

    hipLaunchKernelGGL(subemb_kernel, dim3(6400), dim3(256), 0, stream, xall, sub, out + OFF_SUB);
    hipLaunchKernelGGL(relemb_kernel, dim3(6400), dim3(256), 0, stream, init_rel, rel, out + OFF_REL);
    hipLaunchKernelGGL(club_kernel, dim3(256, 6), dim3(256), 0, stream, out + OFF_SUB, perm,
                       mu_w1, mu_b1, mu_w2, mu_b2, lv_w1, lv_b1, lv_w2, lv_b2, loss);
    hipLaunchKernelGGL(loss_out_kernel, dim3(1), dim3(64), 0, stream, loss, out + OFF_MI);
}

// Round 6
// 1528.989 us; speedup vs baseline: 1.5959x; 1.2103x over previous
//
#include <hip/hip_runtime.h>
#include <hip/hip_bf16.h>

#define N_NODES 40000
#define INIT_D  100
#define DD      200
#define FF      4
#define EE      800000
#define NRELS   800
#define BB      2048
#define H2D     100
#define FD      800   // F*D

typedef __hip_bfloat16 bf16;
typedef unsigned char u8;
typedef unsigned int u32;
typedef float floatx2 __attribute__((ext_vector_type(2)));
typedef float floatx4 __attribute__((ext_vector_type(4)));

#define XSCALE 256.f
#define XINV   (1.f / 256.f)

__device__ __forceinline__ float b2f(bf16 v) { return __bfloat162float(v); }

__device__ __forceinline__ void fp8x4_dec(u32 q, float* o) {
    floatx2 lo = __builtin_amdgcn_cvt_pk_f32_fp8((int)q, false);
    floatx2 hi = __builtin_amdgcn_cvt_pk_f32_fp8((int)q, true);
    o[0] = lo.x; o[1] = lo.y; o[2] = hi.x; o[3] = hi.y;
}

__device__ __forceinline__ u32 fp8x4_enc(float v0, float v1, float v2, float v3) {
    int o = 0;
    o = __builtin_amdgcn_cvt_pk_fp8_f32(v0, v1, o, false);
    o = __builtin_amdgcn_cvt_pk_fp8_f32(v2, v3, o, true);
    return (u32)o;
}

// ---------------- setup ----------------
__global__ __launch_bounds__(256) void zero_kernel(int* count, int* cursor, double* loss) {
    int idx = blockIdx.x * 256 + threadIdx.x;
    if (idx < N_NODES) { count[idx] = 0; cursor[idx] = 0; }
    if (idx == 0) *loss = 0.0;
}

// ---------------- x0 = tanh(init_embed @ pca_w + pca_b) ----------------
// grid (13, 2500), block 64. mode 0: fp8 (scaled); mode 1: f32.
__global__ __launch_bounds__(64) void pca_kernel(const float* __restrict__ emb,
                                                 const float* __restrict__ pw,
                                                 const float* __restrict__ pb,
                                                 u8* __restrict__ xq,
                                                 float* __restrict__ xf,
                                                 int mode) {
    __shared__ float es[16][INIT_D];
    int r0 = blockIdx.y * 16;
    int c  = blockIdx.x * 64 + threadIdx.x;
    for (int idx = threadIdx.x; idx < 16 * INIT_D; idx += 64) {
        int r = idx / INIT_D, k = idx % INIT_D;
        es[r][k] = emb[(size_t)(r0 + r) * INIT_D + k];
    }
    __syncthreads();
    if (c >= FD) return;
    float acc[16];
#pragma unroll
    for (int r = 0; r < 16; r++) acc[r] = 0.f;
    for (int k = 0; k < INIT_D; k++) {
        float w = pw[k * FD + c];
#pragma unroll
        for (int r = 0; r < 16; r++) acc[r] += es[r][k] * w;
    }
    float bias = pb[c];
#pragma unroll
    for (int r = 0; r < 16; r++) {
        float v = tanhf(acc[r] + bias);
        if (mode == 0) {
            int t8 = __builtin_amdgcn_cvt_pk_fp8_f32(v * XSCALE, 0.f, 0, false);
            xq[(size_t)(r0 + r) * FD + c] = (u8)(t8 & 0xFF);
        } else {
            xf[(size_t)(r0 + r) * FD + c] = v;
        }
    }
}

// ---------------- kw fast: fp8 x, wave = 16 rows (4 nodes) x 200 cols -----------
// xr viewed as [160000][200] fp8 (row = n*4+f). grid 2500, block 256 (4 waves).
// Wave-private LDS region -> no __syncthreads needed (in-wave LDS ordering).
__global__ __launch_bounds__(256) void kw_fast(const u8* __restrict__ xr,
                                               const float* __restrict__ cw,
                                               u8* __restrict__ kwout) {
    __shared__ float as[4][16][100];
    int wv = threadIdx.x >> 6, lane = threadIdx.x & 63;
    int g = blockIdx.x * 4 + wv;
    size_t rowbase = (size_t)g * 16;
    float acc[16][4];
#pragma unroll
    for (int r = 0; r < 16; r++)
#pragma unroll
        for (int i = 0; i < 4; i++) acc[r][i] = 0.f;
    int cc[4], cl[4];
#pragma unroll
    for (int i = 0; i < 4; i++) { cc[i] = i * 64 + lane; cl[i] = cc[i] < DD ? cc[i] : DD - 1; }
    for (int kc = 0; kc < 2; kc++) {
        for (int j = lane; j < 400; j += 64) {
            int rr = j / 25, k4 = (j % 25) * 4;
            u32 q = *(const u32*)(xr + (rowbase + rr) * DD + kc * 100 + k4);
            float dv[4];
            fp8x4_dec(q, dv);
            as[wv][rr][k4]     = dv[0];
            as[wv][rr][k4 + 1] = dv[1];
            as[wv][rr][k4 + 2] = dv[2];
            as[wv][rr][k4 + 3] = dv[3];
        }
        for (int kk = 0; kk < 100; kk++) {
            int k = kc * 100 + kk;
            float w0 = cw[k * DD + cl[0]];
            float w1 = cw[k * DD + cl[1]];
            float w2 = cw[k * DD + cl[2]];
            float w3 = cw[k * DD + cl[3]];
#pragma unroll
            for (int r = 0; r < 16; r++) {
                float a = as[wv][r][kk];
                acc[r][0] += a * w0; acc[r][1] += a * w1;
                acc[r][2] += a * w2; acc[r][3] += a * w3;
            }
        }
    }
#pragma unroll
    for (int j = 0; j < 4; j++) {
        int n = g * 4 + j;
#pragma unroll
        for (int i = 0; i < 4; i++) {
            if (cc[i] >= DD) continue;
            float v0 = acc[j * 4 + 0][i] * XINV, v1 = acc[j * 4 + 1][i] * XINV;
            float v2 = acc[j * 4 + 2][i] * XINV, v3 = acc[j * 4 + 3][i] * XINV;
            v0 = v0 > 0.f ? v0 : 0.2f * v0;
            v1 = v1 > 0.f ? v1 : 0.2f * v1;
            v2 = v2 > 0.f ? v2 : 0.2f * v2;
            v3 = v3 > 0.f ? v3 : 0.2f * v3;
            float m = fmaxf(fmaxf(v0, v1), fmaxf(v2, v3));
            float e0 = __expf(v0 - m), e1 = __expf(v1 - m);
            float e2 = __expf(v2 - m), e3 = __expf(v3 - m);
            float inv = 1.f / (e0 + e1 + e2 + e3);
            size_t base = (size_t)n * FD + cc[i];
            kwout[base]          = (u8)(e0 * inv * 255.f + 0.5f);
            kwout[base + DD]     = (u8)(e1 * inv * 255.f + 0.5f);
            kwout[base + 2 * DD] = (u8)(e2 * inv * 255.f + 0.5f);
            kwout[base + 3 * DD] = (u8)(e3 * inv * 255.f + 0.5f);
        }
    }
}

// ---------------- kw fallback: wave-per-node, f32 x ----------------
__global__ __launch_bounds__(256) void kw_old(const float* __restrict__ x,
                                              const float* __restrict__ cw,
                                              u8* __restrict__ kw) {
    int wave = threadIdx.x >> 6, lane = threadIdx.x & 63;
    int n = blockIdx.x * 4 + wave;
    const float* xp = x + (size_t)n * FD;
    float acc[4][4];
#pragma unroll
    for (int f = 0; f < 4; f++)
#pragma unroll
        for (int i = 0; i < 4; i++) acc[f][i] = 0.f;
    for (int k = 0; k < DD; k++) {
        float xv0 = xp[k], xv1 = xp[DD + k];
        float xv2 = xp[2 * DD + k], xv3 = xp[3 * DD + k];
#pragma unroll
        for (int i = 0; i < 4; i++) {
            int d = i * 64 + lane;
            float w = (d < DD) ? cw[k * DD + d] : 0.f;
            acc[0][i] += xv0 * w; acc[1][i] += xv1 * w;
            acc[2][i] += xv2 * w; acc[3][i] += xv3 * w;
        }
    }
    u8* kwp = kw + (size_t)n * FD;
#pragma unroll
    for (int i = 0; i < 4; i++) {
        int d = i * 64 + lane;
        if (d >= DD) continue;
        float v0 = acc[0][i], v1 = acc[1][i], v2 = acc[2][i], v3 = acc[3][i];
        v0 = v0 > 0.f ? v0 : 0.2f * v0;
        v1 = v1 > 0.f ? v1 : 0.2f * v1;
        v2 = v2 > 0.f ? v2 : 0.2f * v2;
        v3 = v3 > 0.f ? v3 : 0.2f * v3;
        float m = fmaxf(fmaxf(v0, v1), fmaxf(v2, v3));
        float e0 = __expf(v0 - m), e1 = __expf(v1 - m), e2 = __expf(v2 - m), e3 = __expf(v3 - m);
        float inv = 1.f / (e0 + e1 + e2 + e3);
        kwp[d]          = (u8)(e0 * inv * 255.f + 0.5f);
        kwp[DD + d]     = (u8)(e1 * inv * 255.f + 0.5f);
        kwp[2 * DD + d] = (u8)(e2 * inv * 255.f + 0.5f);
        kwp[3 * DD + d] = (u8)(e3 * inv * 255.f + 0.5f);
    }
}

// ---------------- CSR build (packed: etype<<16 | src) ----------------
__global__ __launch_bounds__(256) void count_kernel(const int* __restrict__ dst, int* count) {
    int e = blockIdx.x * 256 + threadIdx.x;
    atomicAdd(&count[dst[e]], 1);
}

__global__ __launch_bounds__(1024) void scan_kernel(const int* __restrict__ count, int* __restrict__ offs) {
    __shared__ int buf[1024];
    __shared__ int carry_s;
    int tid = threadIdx.x;
    if (tid == 0) { carry_s = 0; offs[0] = 0; }
    __syncthreads();
    for (int base = 0; base < 40960; base += 1024) {
        int i = base + tid;
        int v = (i < N_NODES) ? count[i] : 0;
        buf[tid] = v;
        __syncthreads();
        for (int off = 1; off < 1024; off <<= 1) {
            int t = (tid >= off) ? buf[tid - off] : 0;
            __syncthreads();
            buf[tid] += t;
            __syncthreads();
        }
        int incl = buf[tid] + carry_s;
        if (i < N_NODES) offs[i + 1] = incl;
        __syncthreads();
        if (tid == 1023) carry_s = incl;
        __syncthreads();
    }
}

__global__ __launch_bounds__(256) void scatter_kernel(const int* __restrict__ src,
                                                      const int* __restrict__ dst,
                                                      const int* __restrict__ etyp,
                                                      const int* __restrict__ offs,
                                                      int* cursor,
                                                      u32* __restrict__ ep) {
    int e = blockIdx.x * 256 + threadIdx.x;
    int d = dst[e];
    int p = offs[d] + atomicAdd(&cursor[d], 1);
    ep[p] = ((u32)etyp[e] << 16) | (u32)src[e];
}

// ---------------- fast agg: fp8 gathers, no online-rescale (logits bounded) -------
// lane owns d = lane*4 .. lane*4+3 (lanes 50..63 idle). mode 0: fp8 out; 1: f32 out.
__global__ __launch_bounds__(256) void agg_fp8(const u8* __restrict__ xin,
                                               const u8* __restrict__ kwv,
                                               const float* __restrict__ r,
                                               const int* __restrict__ offs,
                                               const u32* __restrict__ ep,
                                               u8* __restrict__ xoq,
                                               float* __restrict__ xof,
                                               int mode) {
    int n    = blockIdx.x * 4 + (threadIdx.x >> 6);   // 40000 waves
    int lane = threadIdx.x & 63;
    bool act = lane < 50;
    int db = lane * 4;
    const u8* xdp = xin + (size_t)n * FD;
    float xd[4][4], A[4][4], Sm[4];
#pragma unroll
    for (int f = 0; f < 4; f++) {
        Sm[f] = 0.f;
        u32 q = act ? *(const u32*)(xdp + f * DD + db) : 0u;
        fp8x4_dec(q, xd[f]);
        A[f][0] = A[f][1] = A[f][2] = A[f][3] = 0.f;
    }
    int e0 = offs[n], e1 = offs[n + 1];
    for (int e = e0; e < e1; ++e) {
        u32 wrd = ep[e];
        int s = wrd & 0xFFFF, t = wrd >> 16;
        const u8* xsp = xin + (size_t)s * FD;
        float rr[4];
        if (act) {
            floatx4 rv = *(const floatx4*)(r + t * DD + db);
            rr[0] = rv.x; rr[1] = rv.y; rr[2] = rv.z; rr[3] = rv.w;
        } else {
            rr[0] = rr[1] = rr[2] = rr[3] = 0.f;
        }
        float mm[4][4], p[4];
#pragma unroll
        for (int f = 0; f < 4; f++) {
            u32 q = act ? *(const u32*)(xsp + f * DD + db) : 0u;
            float sx[4];
            fp8x4_dec(q, sx);
            mm[f][0] = sx[0] * rr[0]; mm[f][1] = sx[1] * rr[1];
            mm[f][2] = sx[2] * rr[2]; mm[f][3] = sx[3] * rr[3];
            p[f] = mm[f][0] * xd[f][0] + mm[f][1] * xd[f][1]
                 + mm[f][2] * xd[f][2] + mm[f][3] * xd[f][3];
        }
#pragma unroll
        for (int o = 32; o > 0; o >>= 1) {
            p[0] += __shfl_xor(p[0], o, 64);
            p[1] += __shfl_xor(p[1], o, 64);
            p[2] += __shfl_xor(p[2], o, 64);
            p[3] += __shfl_xor(p[3], o, 64);
        }
#pragma unroll
        for (int f = 0; f < 4; f++) {
            // p is scaled by S^2 (both x's fp8-scaled); leaky commutes with +scale
            float lg = (p[f] > 0.f ? p[f] : 0.2f * p[f]) * (XINV * XINV);
            float w = __expf(lg);
            Sm[f] += w;
            A[f][0] += w * mm[f][0]; A[f][1] += w * mm[f][1];
            A[f][2] += w * mm[f][2]; A[f][3] += w * mm[f][3];
        }
    }
    const u8* kwp = kwv + (size_t)n * FD;
#pragma unroll
    for (int f = 0; f < 4; f++) {
        float inv = 1.f / (Sm[f] + 1e-16f);
        if (act) {
            float v[4];
#pragma unroll
            for (int j = 0; j < 4; j++) {
                float kv = (float)kwp[f * DD + db + j] * (1.f / 255.f);
                v[j] = tanhf(A[f][j] * inv * XINV) * kv;   // A scaled by S
            }
            if (mode == 0) {
                u32 o = fp8x4_enc(v[0] * XSCALE, v[1] * XSCALE, v[2] * XSCALE, v[3] * XSCALE);
                *(u32*)(xoq + (size_t)n * FD + f * DD + db) = o;
            } else {
                floatx4 o4;
                o4.x = v[0]; o4.y = v[1]; o4.z = v[2]; o4.w = v[3];
                *(floatx4*)(xof + (size_t)n * FD + f * DD + db) = o4;
            }
        }
    }
}

// ---------------- fallback sliced agg (f32) + copyback ----------------
__global__ __launch_bounds__(256) void agg_sliced(const float* __restrict__ xall,
                                                  const u8* __restrict__ kw,
                                                  const float* __restrict__ r,
                                                  const int* __restrict__ offs,
                                                  const u32* __restrict__ ep,
                                                  bf16* __restrict__ xtmp,
                                                  int f) {
    int n    = blockIdx.x * 4 + (threadIdx.x >> 6);
    int lane = threadIdx.x & 63;
    const float* xdp = xall + (size_t)n * FD + f * DD;
    float xd[4];
#pragma unroll
    for (int i = 0; i < 4; i++) {
        int d = i * 64 + lane;
        xd[i] = (d < DD) ? xdp[d] : 0.f;
    }
    float M = -INFINITY, S = 0.f;
    float A0 = 0.f, A1 = 0.f, A2 = 0.f, A3 = 0.f;
    int e0 = offs[n], e1 = offs[n + 1];
    for (int e = e0; e < e1; ++e) {
        u32 wrd = ep[e];
        int s = wrd & 0xFFFF, t = wrd >> 16;
        const float* xsp = xall + (size_t)s * FD + f * DD;
        const float* rp = r + t * DD;
        float mm[4];
        float p = 0.f;
#pragma unroll
        for (int i = 0; i < 4; i++) {
            int d = i * 64 + lane;
            float xs = (d < DD) ? xsp[d] : 0.f;
            float rrv = (d < DD) ? rp[d] : 0.f;
            mm[i] = xs * rrv;
            p += mm[i] * xd[i];
        }
#pragma unroll
        for (int o = 32; o > 0; o >>= 1) p += __shfl_xor(p, o, 64);
        float logit = p > 0.f ? p : 0.2f * p;
        float nm = fmaxf(M, logit);
        float sc = __expf(M - nm);
        float w  = __expf(logit - nm);
        S  = S * sc + w;
        A0 = A0 * sc + w * mm[0];
        A1 = A1 * sc + w * mm[1];
        A2 = A2 * sc + w * mm[2];
        A3 = A3 * sc + w * mm[3];
        M = nm;
    }
    float inv = 1.f / (S + 1e-16f);
    const u8* kwp = kw + (size_t)n * FD + f * DD;
    bf16* xo = xtmp + (size_t)n * DD;
    float A[4] = {A0, A1, A2, A3};
#pragma unroll
    for (int i = 0; i < 4; i++) {
        int d = i * 64 + lane;
        if (d < DD) {
            float kv = (float)kwp[d] * (1.f / 255.f);
            xo[d] = __float2bfloat16(tanhf(A[i] * inv) * kv);
        }
    }
}

__global__ __launch_bounds__(256) void copyback_kernel(const bf16* __restrict__ xtmp,
                                                       float* __restrict__ xall, int f) {
    int idx = blockIdx.x * 256 + threadIdx.x;   // 8,000,000
    int n = idx / DD, d = idx % DD;
    xall[(size_t)n * FD + f * DD + d] = b2f(xtmp[idx]);
}

// ---------------- r1 = init_rel @ w_rel[0] ----------------
__global__ __launch_bounds__(256) void rmul_kernel(const float* __restrict__ r0,
                                                   const float* __restrict__ w,
                                                   float* __restrict__ r1) {
    __shared__ float row[DD];
    int n = blockIdx.x;
    if (threadIdx.x < DD) row[threadIdx.x] = r0[n * DD + threadIdx.x];
    __syncthreads();
    int d = threadIdx.x;
    if (d >= DD) return;
    float acc = 0.f;
    for (int k = 0; k < DD; k++) acc += row[k] * w[k * DD + d];
    r1[n * DD + d] = acc;
}

// ---------------- outputs (f32) ----------------
__global__ __launch_bounds__(256) void subemb_kernel(const float* __restrict__ x,
                                                     const int* __restrict__ sub,
                                                     float* __restrict__ out) {
    int idx = blockIdx.x * 256 + threadIdx.x;   // 1,638,400
    int b = idx / FD, c = idx % FD;
    out[idx] = x[(size_t)sub[b] * FD + c];
}

__global__ __launch_bounds__(256) void relemb_kernel(const float* __restrict__ ir,
                                                     const int* __restrict__ rel,
                                                     float* __restrict__ out) {
    int idx = blockIdx.x * 256 + threadIdx.x;   // 1,638,400
    int b = idx / FD, d = idx % DD;
    out[idx] = ir[(size_t)rel[b] * DD + d];
}

// ---------------- CLUB loss ----------------
__global__ __launch_bounds__(256) void club_kernel(const float* __restrict__ se,
                                                   const int* __restrict__ perm,
                                                   const float* __restrict__ mu_w1, const float* __restrict__ mu_b1,
                                                   const float* __restrict__ mu_w2, const float* __restrict__ mu_b2,
                                                   const float* __restrict__ lv_w1, const float* __restrict__ lv_b1,
                                                   const float* __restrict__ lv_w2, const float* __restrict__ lv_b2,
                                                   double* loss) {
    const int PI[6] = {0, 0, 0, 1, 1, 2};
    const int PJ[6] = {1, 2, 3, 2, 3, 3};
    int p = blockIdx.y;
    int i = PI[p], j = PJ[p];
    __shared__ float xi[DD], yj[DD], yjp[DD], h1m[H2D], h1v[H2D];
    __shared__ float wsum[4];
    float psum = 0.f;
    for (int rr = 0; rr < 8; ++rr) {
        int b = blockIdx.x * 8 + rr;
        int bp = perm[b];
        if (threadIdx.x < DD) {
            int t = threadIdx.x;
            xi[t]  = se[(size_t)b * FD + i * DD + t];
            yj[t]  = se[(size_t)b * FD + j * DD + t];
            yjp[t] = se[(size_t)bp * FD + j * DD + t];
        }
        __syncthreads();
        if (threadIdx.x < H2D) {
            int c = threadIdx.x;
            float a1 = mu_b1[p * H2D + c];
            float a2 = lv_b1[p * H2D + c];
            for (int d = 0; d < DD; d++) {
                float xv = xi[d];
                a1 += xv * mu_w1[(size_t)p * DD * H2D + d * H2D + c];
                a2 += xv * lv_w1[(size_t)p * DD * H2D + d * H2D + c];
            }
            h1m[c] = fmaxf(a1, 0.f);
            h1v[c] = fmaxf(a2, 0.f);
        }
        __syncthreads();
        if (threadIdx.x < DD) {
            int d = threadIdx.x;
            float m = mu_b2[p * DD + d];
            float v = lv_b2[p * DD + d];
            for (int c = 0; c < H2D; c++) {
                m += h1m[c] * mu_w2[(size_t)p * H2D * DD + c * DD + d];
                v += h1v[c] * lv_w2[(size_t)p * H2D * DD + c * DD + d];
            }
            float lv = tanhf(v);
            float ivr = __expf(-lv);
            float d1 = m - yj[d], d2 = m - yjp[d];
            psum += (d2 * d2 - d1 * d1) * ivr;
        }
        __syncthreads();
    }
    float v = psum;
#pragma unroll
    for (int o = 32; o > 0; o >>= 1) v += __shfl_xor(v, o, 64);
    if ((threadIdx.x & 63) == 0) wsum[threadIdx.x >> 6] = v;
    __syncthreads();
    if (threadIdx.x == 0) {
        double t = (double)wsum[0] + (double)wsum[1] + (double)wsum[2] + (double)wsum[3];
        atomicAdd(loss, t / (2.0 * (double)BB));
    }
}

__global__ void loss_out_kernel(const double* loss, float* out) {
    if (threadIdx.x == 0 && blockIdx.x == 0)
        out[0] = (float)(*loss);
}

// ---------------- launch ----------------
extern "C" void kernel_launch(void* const* d_in, const int* in_sizes, int n_in,
                              void* d_out, int out_size, void* d_ws, size_t ws_size,
                              hipStream_t stream) {
    const int* sub  = (const int*)d_in[0];
    const int* rel  = (const int*)d_in[1];
    const int* eidx = (const int*)d_in[2];
    const int* etyp = (const int*)d_in[3];
    const int* perm = (const int*)d_in[4];
    const float* init_embed = (const float*)d_in[5];
    const float* init_rel   = (const float*)d_in[6];
    const float* pca_w = (const float*)d_in[7];
    const float* pca_b = (const float*)d_in[8];
    const float* cw_w  = (const float*)d_in[9];
    const float* w_rel = (const float*)d_in[10];
    const float* mu_w1 = (const float*)d_in[11];
    const float* mu_b1 = (const float*)d_in[12];
    const float* mu_w2 = (const float*)d_in[13];
    const float* mu_b2 = (const float*)d_in[14];
    const float* lv_w1 = (const float*)d_in[15];
    const float* lv_b1 = (const float*)d_in[16];
    const float* lv_w2 = (const float*)d_in[17];
    const float* lv_b2 = (const float*)d_in[18];

    float* out = (float*)d_out;
    const size_t OFF_SUB = 0;
    const size_t OFF_REL = 1638400;
    const size_t OFF_X   = 3276800;
    const size_t OFF_MI  = 35276800;
    float* xall = out + OFF_X;

    const int* src = eidx;
    const int* dst = eidx + EE;

    bool fast = (ws_size >= (size_t)101 * 1000 * 1000);

    char* w = (char*)d_ws;
    u8* xq0 = nullptr; u8* xq1 = nullptr; bf16* xtmp = nullptr;
    if (fast) {
        xq0 = (u8*)w; w += (size_t)N_NODES * FD;   // 32 MB
        xq1 = (u8*)w; w += (size_t)N_NODES * FD;   // 32 MB
    } else {
        xtmp = (bf16*)w; w += (size_t)N_NODES * DD * 2;   // 16 MB
    }
    u8*   kwb  = (u8*)w;    w += (size_t)N_NODES * FD;    // 32 MB
    float* r1  = (float*)w; w += NRELS * DD * 4;
    u32* ep    = (u32*)w;   w += EE * 4;
    int* count = (int*)w;   w += N_NODES * 4;
    int* offs  = (int*)w;   w += (N_NODES + 16) * 4;
    int* cursor= (int*)w;   w += N_NODES * 4;
    double* loss = (double*)w; w += 256;

    hipLaunchKernelGGL(zero_kernel, dim3(157), dim3(256), 0, stream, count, cursor, loss);
    hipLaunchKernelGGL(pca_kernel, dim3(13, 2500), dim3(64), 0, stream,
                       init_embed, pca_w, pca_b, xq0, xall, fast ? 0 : 1);
    if (fast) hipLaunchKernelGGL(kw_fast, dim3(2500), dim3(256), 0, stream, xq0, cw_w, kwb);
    else      hipLaunchKernelGGL(kw_old, dim3(10000), dim3(256), 0, stream, xall, cw_w, kwb);
    hipLaunchKernelGGL(count_kernel, dim3(3125), dim3(256), 0, stream, dst, count);
    hipLaunchKernelGGL(scan_kernel, dim3(1), dim3(1024), 0, stream, count, offs);
    hipLaunchKernelGGL(scatter_kernel, dim3(3125), dim3(256), 0, stream, src, dst, etyp, offs, cursor, ep);
    hipLaunchKernelGGL(rmul_kernel, dim3(800), dim3(256), 0, stream, init_rel, w_rel, r1);

    if (fast) {
        // layer 0: xq0 -> xq1 (fp8), layer 1: xq1 -> xall (f32, final)
        hipLaunchKernelGGL(agg_fp8, dim3(10000), dim3(256), 0, stream,
                           xq0, kwb, init_rel, offs, ep, xq1, (float*)nullptr, 0);
        hipLaunchKernelGGL(agg_fp8, dim3(10000), dim3(256), 0, stream,
                           xq1, kwb, r1, offs, ep, (u8*)nullptr, xall, 1);
    } else {
        for (int f = 0; f < FF; f++) {
            hipLaunchKernelGGL(agg_sliced, dim3(10000), dim3(256), 0, stream,
                               xall, kwb, init_rel, offs, ep, xtmp, f);
            hipLaunchKernelGGL(copyback_kernel, dim3(31250), dim3(256), 0, stream, xtmp, xall, f);
        }
        for (int f = 0; f < FF; f++) {
            hipLaunchKernelGGL(agg_sliced, dim3(10000), dim3(256), 0, stream,
                               xall, kwb, r1, offs, ep, xtmp, f);
            hipLaunchKernelGGL(copyback_kernel, dim3(31250), dim3(256), 0, stream, xtmp, xall, f);
        }
    }

    hipLaunchKernelGGL(subemb_kernel, dim3(6400), dim3(256), 0, stream, xall, sub, out + OFF_SUB);
    hipLaunchKernelGGL(relemb_kernel, dim3(6400), dim3(256), 0, stream, init_rel, rel, out + OFF_REL);
    hipLaunchKernelGGL(club_kernel, dim3(256, 6), dim3(256), 0, stream, out + OFF_SUB, perm,
                       mu_w1, mu_b1, mu_w2, mu_b2, lv_w1, lv_b1, lv_w2, lv_b2, loss);
    hipLaunchKernelGGL(loss_out_kernel, dim3(1), dim3(64), 0, stream, loss, out + OFF_MI);
}